// Round 1
// baseline (442.318 us; speedup 1.0000x reference)
//
#include <hip/hip_runtime.h>

typedef unsigned short u16;
typedef __bf16 bf16x8 __attribute__((ext_vector_type(8)));
typedef float f32x4 __attribute__((ext_vector_type(4)));

#define D_MODEL 1024
#define S_LEN 2048
#define NH 16
#define DK 64
#define BATCH 2
#define M_ROWS (BATCH * S_LEN) /* 4096 */
#define NQKV (3 * D_MODEL)     /* 3072 */

__device__ __forceinline__ u16 f2bf(float x) {
  union { float f; unsigned u; } v; v.f = x;
  unsigned r = v.u + 0x7fffu + ((v.u >> 16) & 1u);  // RNE
  return (u16)(r >> 16);
}

// ---------------- pack f32 -> bf16 (coalesced, 8 elems/thread) ----------------
__global__ __launch_bounds__(256) void pack_bf16(const float* __restrict__ in, u16* __restrict__ out) {
  const int idx = (blockIdx.x * 256 + threadIdx.x) * 8;
  float4 a = *(const float4*)&in[idx];
  float4 b = *(const float4*)&in[idx + 4];
  unsigned p0 = (unsigned)f2bf(a.x) | ((unsigned)f2bf(a.y) << 16);
  unsigned p1 = (unsigned)f2bf(a.z) | ((unsigned)f2bf(a.w) << 16);
  unsigned p2 = (unsigned)f2bf(b.x) | ((unsigned)f2bf(b.y) << 16);
  unsigned p3 = (unsigned)f2bf(b.z) | ((unsigned)f2bf(b.w) << 16);
  int4 o; o.x = (int)p0; o.y = (int)p1; o.z = (int)p2; o.w = (int)p3;
  *(int4*)&out[idx] = o;
}

// -------- tiled transpose + pack: in f32 [R,C] -> out bf16 [C,R] --------
__global__ __launch_bounds__(256) void transpose_pack(const float* __restrict__ in, u16* __restrict__ out,
                                                      int R, int C) {
  __shared__ u16 T[64][68];
  const int r0 = blockIdx.x * 64, c0 = blockIdx.y * 64;
  const int t = threadIdx.x;
  const int col = t & 63, rq = t >> 6;  // 4 rows per step
#pragma unroll
  for (int s = 0; s < 16; ++s) {
    int row = s * 4 + rq;
    T[col][row] = f2bf(in[(size_t)(r0 + row) * C + c0 + col]);
  }
  __syncthreads();
#pragma unroll
  for (int s = 0; s < 16; ++s) {
    int crow = s * 4 + rq;
    out[(size_t)(c0 + crow) * R + r0 + col] = T[crow][col];
  }
}

// -------- bf16 GEMM: C[M,N] = A[M,K] * BT[N,K]^T + bias; 128x128 tile, BK=64 --------
template <int OUTF32>
__global__ __launch_bounds__(256) void gemm_bt(const u16* __restrict__ A, const u16* __restrict__ BT,
                                               const float* __restrict__ bias, void* __restrict__ outp,
                                               int K, int N) {
  __shared__ u16 As[128][72];
  __shared__ u16 Bs[128][72];
  const int m0 = blockIdx.x * 128, n0 = blockIdx.y * 128;
  const int t = threadIdx.x, lane = t & 63, w = t >> 6;
  const int wr = w >> 1, wc = w & 1;
  const int l15 = lane & 15, l4 = lane >> 4;
  const int rB = t >> 3, c8 = (t & 7) * 8;  // staging: 32 rows/pass, 8-elem chunks
  f32x4 acc[4][4] = {};
  for (int k0 = 0; k0 < K; k0 += 64) {
    int4 ra[4], rb[4];
#pragma unroll
    for (int s = 0; s < 4; ++s) {
      int row = s * 32 + rB;
      ra[s] = *(const int4*)&A[(size_t)(m0 + row) * K + k0 + c8];
      rb[s] = *(const int4*)&BT[(size_t)(n0 + row) * K + k0 + c8];
    }
    __syncthreads();  // protect previous tile's readers
#pragma unroll
    for (int s = 0; s < 4; ++s) {
      int row = s * 32 + rB;
      *(int4*)&As[row][c8] = ra[s];
      *(int4*)&Bs[row][c8] = rb[s];
    }
    __syncthreads();
#pragma unroll
    for (int ks = 0; ks < 2; ++ks) {
      bf16x8 af[4], bfr[4];
#pragma unroll
      for (int g = 0; g < 4; ++g) {
        af[g]  = *(const bf16x8*)&As[wr * 64 + g * 16 + l15][ks * 32 + l4 * 8];
        bfr[g] = *(const bf16x8*)&Bs[wc * 64 + g * 16 + l15][ks * 32 + l4 * 8];
      }
#pragma unroll
      for (int mg = 0; mg < 4; ++mg)
#pragma unroll
        for (int ng = 0; ng < 4; ++ng)
          acc[mg][ng] = __builtin_amdgcn_mfma_f32_16x16x32_bf16(af[mg], bfr[ng], acc[mg][ng], 0, 0, 0);
    }
  }
  const int rowb = m0 + wr * 64, colb = n0 + wc * 64;
#pragma unroll
  for (int mg = 0; mg < 4; ++mg)
#pragma unroll
    for (int ng = 0; ng < 4; ++ng) {
      int col = colb + ng * 16 + l15;
      float bv = bias[col];
#pragma unroll
      for (int j = 0; j < 4; ++j) {
        int row = rowb + mg * 16 + l4 * 4 + j;
        float val = acc[mg][ng][j] + bv;
        if (OUTF32) ((float*)outp)[(size_t)row * N + col] = val;
        else        ((u16*)outp)[(size_t)row * N + col] = f2bf(val);
      }
    }
}

// -------- fused attention: scores (f32, normalized) + O = P@V (bf16) --------
// grid: b*NH*16 blocks; block = 256 thr (4 waves), each block 128 q rows, wave = 32 q rows
__global__ __launch_bounds__(256) void attn_fused(const u16* __restrict__ qkv, const float* __restrict__ mask,
                                                  float* __restrict__ scores, u16* __restrict__ attnout) {
  __shared__ u16 Ks[64][72];
  __shared__ u16 Vt[64][72];
  __shared__ u16 Ps[128][72];
  const int bid = blockIdx.x;
  const int qt = bid & 15, h = (bid >> 4) & 15, b = bid >> 8;
  const int t = threadIdx.x, lane = t & 63, w = t >> 6;
  const int l15 = lane & 15, l4 = lane >> 4;
  const float scale = 0.125f;

  // Q fragments, register-resident for whole kernel
  bf16x8 qf[2][2];
#pragma unroll
  for (int mg = 0; mg < 2; ++mg) {
    int qrow = qt * 128 + w * 32 + mg * 16 + l15;
    const u16* qp = &qkv[(size_t)(b * S_LEN + qrow) * NQKV + h * DK];
#pragma unroll
    for (int ks = 0; ks < 2; ++ks) qf[mg][ks] = *(const bf16x8*)&qp[ks * 32 + l4 * 8];
  }

  const int kr = t >> 2, c16 = (t & 3) * 16;  // staging coords (64 rows x 4 chunks)
  float ps[2][4] = {{0.f,0.f,0.f,0.f},{0.f,0.f,0.f,0.f}};

  // ---- pass 1: row sums of exp(logit) (no max-subtract; logits are small) ----
  for (int kt = 0; kt < 32; ++kt) {
    const u16* kp = &qkv[(size_t)(b * S_LEN + kt * 64 + kr) * NQKV + D_MODEL + h * DK + c16];
    int4 ka = *(const int4*)kp;
    int4 kb = *(const int4*)(kp + 8);
    __syncthreads();
    *(int4*)&Ks[kr][c16] = ka;
    *(int4*)&Ks[kr][c16 + 8] = kb;
    __syncthreads();
    f32x4 sacc[2][4] = {};
#pragma unroll
    for (int ks = 0; ks < 2; ++ks) {
      bf16x8 kf[4];
#pragma unroll
      for (int n = 0; n < 4; ++n) kf[n] = *(const bf16x8*)&Ks[n * 16 + l15][ks * 32 + l4 * 8];
#pragma unroll
      for (int mg = 0; mg < 2; ++mg)
#pragma unroll
        for (int n = 0; n < 4; ++n)
          sacc[mg][n] = __builtin_amdgcn_mfma_f32_16x16x32_bf16(qf[mg][ks], kf[n], sacc[mg][n], 0, 0, 0);
    }
#pragma unroll
    for (int n = 0; n < 4; ++n) {
      float mb = -10000.0f * (1.0f - mask[b * S_LEN + kt * 64 + n * 16 + l15]);
#pragma unroll
      for (int mg = 0; mg < 2; ++mg)
#pragma unroll
        for (int j = 0; j < 4; ++j)
          ps[mg][j] += __expf(sacc[mg][n][j] * scale + mb);
    }
  }
  // reduce row sums across the 16 lanes of each l4 group
#pragma unroll
  for (int off = 1; off < 16; off <<= 1)
#pragma unroll
    for (int mg = 0; mg < 2; ++mg)
#pragma unroll
      for (int j = 0; j < 4; ++j)
        ps[mg][j] += __shfl_xor(ps[mg][j], off, 64);
  float inv[2][4];
#pragma unroll
  for (int mg = 0; mg < 2; ++mg)
#pragma unroll
    for (int j = 0; j < 4; ++j) inv[mg][j] = 1.0f / ps[mg][j];

  f32x4 oacc[2][4] = {};
  // ---- pass 2: recompute logits (bitwise-identical), write scores, PV ----
  for (int kt = 0; kt < 32; ++kt) {
    const u16* kp = &qkv[(size_t)(b * S_LEN + kt * 64 + kr) * NQKV + D_MODEL + h * DK + c16];
    const u16* vp = kp + D_MODEL;
    int4 ka = *(const int4*)kp;
    int4 kb = *(const int4*)(kp + 8);
    int4 va = *(const int4*)vp;
    int4 vb4 = *(const int4*)(vp + 8);
    __syncthreads();
    *(int4*)&Ks[kr][c16] = ka;
    *(int4*)&Ks[kr][c16 + 8] = kb;
    {
      const u16* vs0 = (const u16*)&va;
      const u16* vs1 = (const u16*)&vb4;
#pragma unroll
      for (int i = 0; i < 8; ++i) Vt[c16 + i][kr] = vs0[i];
#pragma unroll
      for (int i = 0; i < 8; ++i) Vt[c16 + 8 + i][kr] = vs1[i];
    }
    __syncthreads();
    f32x4 sacc[2][4] = {};
#pragma unroll
    for (int ks = 0; ks < 2; ++ks) {
      bf16x8 kf[4];
#pragma unroll
      for (int n = 0; n < 4; ++n) kf[n] = *(const bf16x8*)&Ks[n * 16 + l15][ks * 32 + l4 * 8];
#pragma unroll
      for (int mg = 0; mg < 2; ++mg)
#pragma unroll
        for (int n = 0; n < 4; ++n)
          sacc[mg][n] = __builtin_amdgcn_mfma_f32_16x16x32_bf16(qf[mg][ks], kf[n], sacc[mg][n], 0, 0, 0);
    }
#pragma unroll
    for (int n = 0; n < 4; ++n) {
      float mb = -10000.0f * (1.0f - mask[b * S_LEN + kt * 64 + n * 16 + l15]);
#pragma unroll
      for (int mg = 0; mg < 2; ++mg) {
        size_t srow = (size_t)((b * NH + h) * S_LEN + qt * 128 + w * 32 + mg * 16 + l4 * 4);
        size_t sbase = srow * S_LEN + (size_t)(kt * 64 + n * 16 + l15);
#pragma unroll
        for (int j = 0; j < 4; ++j) {
          float p = __expf(sacc[mg][n][j] * scale + mb) * inv[mg][j];
          scores[sbase + (size_t)j * S_LEN] = p;
          Ps[w * 32 + mg * 16 + l4 * 4 + j][n * 16 + l15] = f2bf(p);
        }
      }
    }
    // PV: Ps region is per-wave (in-order LDS within wave); Vt synced above
#pragma unroll
    for (int ks = 0; ks < 2; ++ks) {
      bf16x8 pa[2], vfr[4];
#pragma unroll
      for (int mg = 0; mg < 2; ++mg)
        pa[mg] = *(const bf16x8*)&Ps[w * 32 + mg * 16 + l15][ks * 32 + l4 * 8];
#pragma unroll
      for (int dn = 0; dn < 4; ++dn)
        vfr[dn] = *(const bf16x8*)&Vt[dn * 16 + l15][ks * 32 + l4 * 8];
#pragma unroll
      for (int mg = 0; mg < 2; ++mg)
#pragma unroll
        for (int dn = 0; dn < 4; ++dn)
          oacc[mg][dn] = __builtin_amdgcn_mfma_f32_16x16x32_bf16(pa[mg], vfr[dn], oacc[mg][dn], 0, 0, 0);
    }
  }
  // write O (bf16) to workspace in [B*S, D_MODEL] layout for the proj GEMM
#pragma unroll
  for (int mg = 0; mg < 2; ++mg)
#pragma unroll
    for (int dn = 0; dn < 4; ++dn) {
      int row = b * S_LEN + qt * 128 + w * 32 + mg * 16 + l4 * 4;
      int col = h * DK + dn * 16 + l15;
#pragma unroll
      for (int j = 0; j < 4; ++j)
        attnout[(size_t)(row + j) * D_MODEL + col] = f2bf(oacc[mg][dn][j]);
    }
}

extern "C" void kernel_launch(void* const* d_in, const int* in_sizes, int n_in,
                              void* d_out, int out_size, void* d_ws, size_t ws_size,
                              hipStream_t stream) {
  const float* x      = (const float*)d_in[0];
  const float* mask   = (const float*)d_in[1];
  const float* W_attn = (const float*)d_in[2];
  const float* b_attn = (const float*)d_in[3];
  const float* W_proj = (const float*)d_in[4];
  const float* b_proj = (const float*)d_in[5];
  float* out    = (float*)d_out;
  float* scores = out + (size_t)M_ROWS * D_MODEL;

  char* ws = (char*)d_ws;
  u16* xb     = (u16*)ws;                          // 8 MB  : x as bf16 [4096,1024]
  u16* wqkvT  = (u16*)(ws + (size_t)(8  << 20));   // 6 MB  : W_attn^T bf16 [3072,1024]
  u16* wprojT = (u16*)(ws + (size_t)(14 << 20));   // 2 MB  : W_proj^T bf16 [1024,1024]
  u16* qkv    = (u16*)(ws + (size_t)(16 << 20));   // 24 MB : qkv bf16 [4096,3072]
  u16* attnb  = (u16*)(ws + (size_t)(40 << 20));   // 8 MB  : attn out bf16 [4096,1024]

  pack_bf16<<<(M_ROWS * D_MODEL) / (256 * 8), 256, 0, stream>>>(x, xb);
  transpose_pack<<<dim3(D_MODEL / 64, NQKV / 64), 256, 0, stream>>>(W_attn, wqkvT, D_MODEL, NQKV);
  transpose_pack<<<dim3(D_MODEL / 64, D_MODEL / 64), 256, 0, stream>>>(W_proj, wprojT, D_MODEL, D_MODEL);
  gemm_bt<0><<<dim3(M_ROWS / 128, NQKV / 128), 256, 0, stream>>>(xb, wqkvT, b_attn, (void*)qkv, D_MODEL, NQKV);
  attn_fused<<<BATCH * NH * (S_LEN / 128), 256, 0, stream>>>(qkv, mask, scores, attnb);
  gemm_bt<1><<<dim3(M_ROWS / 128, D_MODEL / 128), 256, 0, stream>>>(attnb, wprojT, b_proj, (void*)out, D_MODEL, D_MODEL);
}

// Round 2
// 310.342 us; speedup vs baseline: 1.4253x; 1.4253x over previous
//
#include <hip/hip_runtime.h>

typedef unsigned short u16;
typedef __bf16 bf16x8 __attribute__((ext_vector_type(8)));
typedef float f32x4 __attribute__((ext_vector_type(4)));

#define D_MODEL 1024
#define S_LEN 2048
#define NH 16
#define DK 64
#define BATCH 2
#define M_ROWS (BATCH * S_LEN) /* 4096 */
#define NQKV (3 * D_MODEL)     /* 3072 */

__device__ __forceinline__ u16 f2bf(float x) {
  union { float f; unsigned u; } v; v.f = x;
  unsigned r = v.u + 0x7fffu + ((v.u >> 16) & 1u);  // RNE
  return (u16)(r >> 16);
}
__device__ __forceinline__ float bf2f(u16 b) {
  union { unsigned u; float f; } v; v.u = ((unsigned)b) << 16; return v.f;
}
__device__ __forceinline__ void gload16(const void* g, void* l) {
  __builtin_amdgcn_global_load_lds((const __attribute__((address_space(1))) unsigned int*)g,
                                   (__attribute__((address_space(3))) unsigned int*)l, 16, 0, 0);
}

// ---------------- pack f32 -> bf16 (coalesced, 8 elems/thread) ----------------
__global__ __launch_bounds__(256) void pack_bf16(const float* __restrict__ in, u16* __restrict__ out) {
  const int idx = (blockIdx.x * 256 + threadIdx.x) * 8;
  float4 a = *(const float4*)&in[idx];
  float4 b = *(const float4*)&in[idx + 4];
  unsigned p0 = (unsigned)f2bf(a.x) | ((unsigned)f2bf(a.y) << 16);
  unsigned p1 = (unsigned)f2bf(a.z) | ((unsigned)f2bf(a.w) << 16);
  unsigned p2 = (unsigned)f2bf(b.x) | ((unsigned)f2bf(b.y) << 16);
  unsigned p3 = (unsigned)f2bf(b.z) | ((unsigned)f2bf(b.w) << 16);
  int4 o; o.x = (int)p0; o.y = (int)p1; o.z = (int)p2; o.w = (int)p3;
  *(int4*)&out[idx] = o;
}

// -------- tiled transpose + pack: in f32 [R,C] -> out bf16 [C,R] --------
__global__ __launch_bounds__(256) void transpose_pack(const float* __restrict__ in, u16* __restrict__ out,
                                                      int R, int C) {
  __shared__ u16 T[64][68];
  const int r0 = blockIdx.x * 64, c0 = blockIdx.y * 64;
  const int t = threadIdx.x;
  const int col = t & 63, rq = t >> 6;
#pragma unroll
  for (int s = 0; s < 16; ++s) {
    int row = s * 4 + rq;
    T[col][row] = f2bf(in[(size_t)(r0 + row) * C + c0 + col]);
  }
  __syncthreads();
#pragma unroll
  for (int s = 0; s < 16; ++s) {
    int crow = s * 4 + rq;
    out[(size_t)(c0 + crow) * R + r0 + col] = T[crow][col];
  }
}

// -------- bf16 GEMM: C[M,N] = A[M,K]*BT[N,K]^T + bias; 128x128, BK=64 --------
// 2-phase: global_load_lds prefetch of tile t+1 issued before compute of tile t,
// single vmcnt(0)+barrier per K-step (via __syncthreads). Linear LDS [128][64]
// with XOR chunk-swizzle (source-preswizzled, read-swizzled).
template <int OUTF32>
__global__ __launch_bounds__(256) void gemm_bt(const u16* __restrict__ A, const u16* __restrict__ BT,
                                               const float* __restrict__ bias, void* __restrict__ outp,
                                               int K, int N) {
  __shared__ u16 As[2][128 * 64];
  __shared__ u16 Bs[2][128 * 64];
  const int m0 = blockIdx.x * 128, n0 = blockIdx.y * 128;
  const int t = threadIdx.x, lane = t & 63, w = t >> 6;
  const int wr = w >> 1, wc = w & 1;
  const int l15 = lane & 15, l4 = lane >> 4;
  const int srow = lane >> 3, schunk = lane & 7;

  f32x4 acc[4][4] = {};

#define STAGE_G(buf, k0)                                                        \
  do {                                                                          \
    _Pragma("unroll") for (int i = 0; i < 4; ++i) {                             \
      int r0 = (i * 4 + w) * 8;                                                 \
      int r = r0 + srow;                                                        \
      int sc = (schunk ^ (r & 7)) * 8;                                          \
      gload16(&A[(size_t)(m0 + r) * K + (k0) + sc], &As[buf][r0 * 64]);         \
      gload16(&BT[(size_t)(n0 + r) * K + (k0) + sc], &Bs[buf][r0 * 64]);        \
    }                                                                           \
  } while (0)

  STAGE_G(0, 0);
  __syncthreads();
  const int nk = K / 64;
  int cur = 0;
  for (int t0 = 0; t0 < nk; ++t0) {
    if (t0 + 1 < nk) STAGE_G(cur ^ 1, (t0 + 1) * 64);
#pragma unroll
    for (int ks = 0; ks < 2; ++ks) {
      bf16x8 af[4], bfr[4];
#pragma unroll
      for (int g = 0; g < 4; ++g) {
        int ra = wr * 64 + g * 16 + l15;
        int rb = wc * 64 + g * 16 + l15;
        af[g]  = *(const bf16x8*)&As[cur][ra * 64 + ((ks * 4 + l4) ^ (ra & 7)) * 8];
        bfr[g] = *(const bf16x8*)&Bs[cur][rb * 64 + ((ks * 4 + l4) ^ (rb & 7)) * 8];
      }
#pragma unroll
      for (int mg = 0; mg < 4; ++mg)
#pragma unroll
        for (int ng = 0; ng < 4; ++ng)
          acc[mg][ng] = __builtin_amdgcn_mfma_f32_16x16x32_bf16(af[mg], bfr[ng], acc[mg][ng], 0, 0, 0);
    }
    __syncthreads();
    cur ^= 1;
  }
#undef STAGE_G
  const int rowb = m0 + wr * 64, colb = n0 + wc * 64;
#pragma unroll
  for (int mg = 0; mg < 4; ++mg)
#pragma unroll
    for (int ng = 0; ng < 4; ++ng) {
      int col = colb + ng * 16 + l15;
      float bv = bias[col];
#pragma unroll
      for (int j = 0; j < 4; ++j) {
        int row = rowb + mg * 16 + l4 * 4 + j;
        float val = acc[mg][ng][j] + bv;
        if (OUTF32) ((float*)outp)[(size_t)row * N + col] = val;
        else        ((u16*)outp)[(size_t)row * N + col] = f2bf(val);
      }
    }
}

// -------- fused attention --------
// grid = B*NH*32 blocks (64 q-rows each), 4 waves, wave = 16 q-rows.
// Pass 1: row sums of exp (K double-buffered via global_load_lds, swizzled).
// Pass 2: recompute logits bitwise-identically, P->bf16 in per-wave LDS,
//         coalesced f32 scores stores from LDS, PV via double-buffered V^T.
__global__ __launch_bounds__(256) void attn_fused(const u16* __restrict__ qkv, const float* __restrict__ mask,
                                                  float* __restrict__ scores, u16* __restrict__ attnout) {
  __shared__ u16 Ks[2][64 * 64];
  __shared__ u16 Vt[2][64][72];
  __shared__ u16 Ps[4][16][72];
  const int bid = blockIdx.x;
  const int qt = bid & 31, h = (bid >> 5) & 15, b = bid >> 9;
  const int t = threadIdx.x, lane = t & 63, w = t >> 6;
  const int l15 = lane & 15, l4 = lane >> 4;
  const int srow = lane >> 3, schunk = lane & 7;
  const u16* kbase = qkv + (size_t)b * S_LEN * NQKV + D_MODEL + h * DK;

  // Q fragments, pre-scaled by 1/8 (exact in bf16: exponent shift)
  bf16x8 qf[2];
  {
    const int qrow = qt * 64 + w * 16 + l15;
    const u16* qp = qkv + (size_t)(b * S_LEN + qrow) * NQKV + h * DK;
#pragma unroll
    for (int ks = 0; ks < 2; ++ks) {
      union { bf16x8 v; u16 s[8]; } qa;
      qa.v = *(const bf16x8*)&qp[ks * 32 + l4 * 8];
#pragma unroll
      for (int e = 0; e < 8; ++e) qa.s[e] = f2bf(bf2f(qa.s[e]) * 0.125f);
      qf[ks] = qa.v;
    }
  }

#define STAGE_K(buf, kt)                                                        \
  do {                                                                          \
    _Pragma("unroll") for (int i = 0; i < 2; ++i) {                             \
      int r0 = (i * 4 + w) * 8;                                                 \
      int r = r0 + srow;                                                        \
      int sc = (schunk ^ (r & 7)) * 8;                                          \
      gload16(&kbase[(size_t)((kt) * 64 + r) * NQKV + sc], &Ks[buf][r0 * 64]);  \
    }                                                                           \
  } while (0)

  float ps[4] = {0.f, 0.f, 0.f, 0.f};
  int cur = 0;
  // ---- pass 1 ----
  STAGE_K(0, 0);
  __syncthreads();
  for (int kt = 0; kt < 32; ++kt) {
    if (kt + 1 < 32) STAGE_K(cur ^ 1, kt + 1);
    f32x4 sacc[4] = {};
#pragma unroll
    for (int ks = 0; ks < 2; ++ks) {
      bf16x8 kf[4];
#pragma unroll
      for (int n = 0; n < 4; ++n) {
        int kr = n * 16 + l15;
        kf[n] = *(const bf16x8*)&Ks[cur][kr * 64 + ((ks * 4 + l4) ^ (kr & 7)) * 8];
      }
#pragma unroll
      for (int n = 0; n < 4; ++n)
        sacc[n] = __builtin_amdgcn_mfma_f32_16x16x32_bf16(qf[ks], kf[n], sacc[n], 0, 0, 0);
    }
#pragma unroll
    for (int n = 0; n < 4; ++n) {
      float mb = -10000.0f * (1.0f - mask[b * S_LEN + kt * 64 + n * 16 + l15]);
#pragma unroll
      for (int j = 0; j < 4; ++j) ps[j] += __expf(sacc[n][j] + mb);
    }
    __syncthreads();
    cur ^= 1;
  }
#pragma unroll
  for (int off = 1; off < 16; off <<= 1)
#pragma unroll
    for (int j = 0; j < 4; ++j) ps[j] += __shfl_xor(ps[j], off, 64);
  float inv[4];
#pragma unroll
  for (int j = 0; j < 4; ++j) inv[j] = 1.0f / ps[j];

  // ---- pass 2 ----
  f32x4 oacc[4] = {};
  const u16* vbase = kbase + D_MODEL;
  const int vkr = t >> 2, vc16 = (t & 3) * 16;
  int4 vra, vrb;

  // prologue (cur == 0 after 32 toggles)
  STAGE_K(0, 0);
  {
    const u16* vp = &vbase[(size_t)vkr * NQKV + vc16];
    vra = *(const int4*)vp; vrb = *(const int4*)(vp + 8);
    const u16* s0 = (const u16*)&vra; const u16* s1 = (const u16*)&vrb;
#pragma unroll
    for (int i = 0; i < 8; ++i) Vt[0][vc16 + i][vkr] = s0[i];
#pragma unroll
    for (int i = 0; i < 8; ++i) Vt[0][vc16 + 8 + i][vkr] = s1[i];
  }
  __syncthreads();
  cur = 0;
  for (int kt = 0; kt < 32; ++kt) {
    const bool has_next = (kt + 1 < 32);
    if (has_next) {
      STAGE_K(cur ^ 1, kt + 1);
      const u16* vp = &vbase[(size_t)((kt + 1) * 64 + vkr) * NQKV + vc16];
      vra = *(const int4*)vp; vrb = *(const int4*)(vp + 8);
    }
    f32x4 sacc[4] = {};
#pragma unroll
    for (int ks = 0; ks < 2; ++ks) {
      bf16x8 kf[4];
#pragma unroll
      for (int n = 0; n < 4; ++n) {
        int kr = n * 16 + l15;
        kf[n] = *(const bf16x8*)&Ks[cur][kr * 64 + ((ks * 4 + l4) ^ (kr & 7)) * 8];
      }
#pragma unroll
      for (int n = 0; n < 4; ++n)
        sacc[n] = __builtin_amdgcn_mfma_f32_16x16x32_bf16(qf[ks], kf[n], sacc[n], 0, 0, 0);
    }
#pragma unroll
    for (int n = 0; n < 4; ++n) {
      float mb = -10000.0f * (1.0f - mask[b * S_LEN + kt * 64 + n * 16 + l15]);
#pragma unroll
      for (int j = 0; j < 4; ++j) {
        float p = __expf(sacc[n][j] + mb) * inv[j];
        Ps[w][l4 * 4 + j][n * 16 + l15] = f2bf(p);
      }
    }
    // PV: Ps is wave-private (in-wave LDS order); Vt[cur] staged last iter
#pragma unroll
    for (int ks = 0; ks < 2; ++ks) {
      bf16x8 pa = *(const bf16x8*)&Ps[w][l15][ks * 32 + l4 * 8];
      bf16x8 vfr[4];
#pragma unroll
      for (int dn = 0; dn < 4; ++dn)
        vfr[dn] = *(const bf16x8*)&Vt[cur][dn * 16 + l15][ks * 32 + l4 * 8];
#pragma unroll
      for (int dn = 0; dn < 4; ++dn)
        oacc[dn] = __builtin_amdgcn_mfma_f32_16x16x32_bf16(pa, vfr[dn], oacc[dn], 0, 0, 0);
    }
    // coalesced scores store: re-read P tile row-major, expand to f32
#pragma unroll
    for (int rr = 0; rr < 2; ++rr) {
      int row = rr * 8 + (lane >> 3);
      int c8 = (lane & 7) * 8;
      union { bf16x8 v; u16 s[8]; } pv;
      pv.v = *(const bf16x8*)&Ps[w][row][c8];
      float4 lo, hi;
      lo.x = bf2f(pv.s[0]); lo.y = bf2f(pv.s[1]); lo.z = bf2f(pv.s[2]); lo.w = bf2f(pv.s[3]);
      hi.x = bf2f(pv.s[4]); hi.y = bf2f(pv.s[5]); hi.z = bf2f(pv.s[6]); hi.w = bf2f(pv.s[7]);
      float* sp = &scores[((size_t)((b * NH + h) * S_LEN + qt * 64 + w * 16 + row)) * S_LEN + kt * 64 + c8];
      *(float4*)sp = lo;
      *((float4*)sp + 1) = hi;
    }
    if (has_next) {  // write next V tile (other buffer; its readers finished last iter)
      const u16* s0 = (const u16*)&vra; const u16* s1 = (const u16*)&vrb;
#pragma unroll
      for (int i = 0; i < 8; ++i) Vt[cur ^ 1][vc16 + i][vkr] = s0[i];
#pragma unroll
      for (int i = 0; i < 8; ++i) Vt[cur ^ 1][vc16 + 8 + i][vkr] = s1[i];
    }
    __syncthreads();
    cur ^= 1;
  }
#undef STAGE_K
  // O write (bf16) for proj GEMM
#pragma unroll
  for (int dn = 0; dn < 4; ++dn) {
    int row = b * S_LEN + qt * 64 + w * 16 + l4 * 4;
    int col = h * DK + dn * 16 + l15;
#pragma unroll
    for (int j = 0; j < 4; ++j)
      attnout[(size_t)(row + j) * D_MODEL + col] = f2bf(oacc[dn][j]);
  }
}

extern "C" void kernel_launch(void* const* d_in, const int* in_sizes, int n_in,
                              void* d_out, int out_size, void* d_ws, size_t ws_size,
                              hipStream_t stream) {
  const float* x      = (const float*)d_in[0];
  const float* mask   = (const float*)d_in[1];
  const float* W_attn = (const float*)d_in[2];
  const float* b_attn = (const float*)d_in[3];
  const float* W_proj = (const float*)d_in[4];
  const float* b_proj = (const float*)d_in[5];
  float* out    = (float*)d_out;
  float* scores = out + (size_t)M_ROWS * D_MODEL;

  char* ws = (char*)d_ws;
  u16* xb     = (u16*)ws;                          // 8 MB  : x bf16 [4096,1024]
  u16* wqkvT  = (u16*)(ws + (size_t)(8  << 20));   // 6 MB  : W_attn^T bf16 [3072,1024]
  u16* wprojT = (u16*)(ws + (size_t)(14 << 20));   // 2 MB  : W_proj^T bf16 [1024,1024]
  u16* qkv    = (u16*)(ws + (size_t)(16 << 20));   // 24 MB : qkv bf16 [4096,3072]
  u16* attnb  = (u16*)(ws + (size_t)(40 << 20));   // 8 MB  : attn out bf16 [4096,1024]

  pack_bf16<<<(M_ROWS * D_MODEL) / (256 * 8), 256, 0, stream>>>(x, xb);
  transpose_pack<<<dim3(D_MODEL / 64, NQKV / 64), 256, 0, stream>>>(W_attn, wqkvT, D_MODEL, NQKV);
  transpose_pack<<<dim3(D_MODEL / 64, D_MODEL / 64), 256, 0, stream>>>(W_proj, wprojT, D_MODEL, D_MODEL);
  gemm_bt<0><<<dim3(M_ROWS / 128, NQKV / 128), 256, 0, stream>>>(xb, wqkvT, b_attn, (void*)qkv, D_MODEL, NQKV);
  attn_fused<<<BATCH * NH * (S_LEN / 64), 256, 0, stream>>>(qkv, mask, scores, attnb);
  gemm_bt<1><<<dim3(M_ROWS / 128, D_MODEL / 128), 256, 0, stream>>>(attnb, wprojT, b_proj, (void*)out, D_MODEL, D_MODEL);
}

// Round 3
// 233.542 us; speedup vs baseline: 1.8940x; 1.3288x over previous
//
#include <hip/hip_runtime.h>

typedef unsigned short u16;
typedef __bf16 bf16x8 __attribute__((ext_vector_type(8)));
typedef float f32x4 __attribute__((ext_vector_type(4)));

#define D_MODEL 1024
#define S_LEN 2048
#define NH 16
#define DK 64
#define BATCH 2
#define M_ROWS (BATCH * S_LEN) /* 4096 */
#define NQKV (3 * D_MODEL)     /* 3072 */

__device__ __forceinline__ u16 f2bf(float x) {
  union { __bf16 h; u16 u; } v; v.h = (__bf16)x;  // native cast -> v_cvt_pk_bf16_f32
  return v.u;
}
__device__ __forceinline__ float bf2f(u16 b) {
  union { unsigned u; float f; } v; v.u = ((unsigned)b) << 16; return v.f;
}
__device__ __forceinline__ void gload16(const void* g, void* l) {
  __builtin_amdgcn_global_load_lds((const __attribute__((address_space(1))) unsigned int*)g,
                                   (__attribute__((address_space(3))) unsigned int*)l, 16, 0, 0);
}

// ---------------- pack f32 -> bf16 (coalesced, 8 elems/thread) ----------------
__global__ __launch_bounds__(256) void pack_bf16(const float* __restrict__ in, u16* __restrict__ out) {
  const int idx = (blockIdx.x * 256 + threadIdx.x) * 8;
  float4 a = *(const float4*)&in[idx];
  float4 b = *(const float4*)&in[idx + 4];
  unsigned p0 = (unsigned)f2bf(a.x) | ((unsigned)f2bf(a.y) << 16);
  unsigned p1 = (unsigned)f2bf(a.z) | ((unsigned)f2bf(a.w) << 16);
  unsigned p2 = (unsigned)f2bf(b.x) | ((unsigned)f2bf(b.y) << 16);
  unsigned p3 = (unsigned)f2bf(b.z) | ((unsigned)f2bf(b.w) << 16);
  int4 o; o.x = (int)p0; o.y = (int)p1; o.z = (int)p2; o.w = (int)p3;
  *(int4*)&out[idx] = o;
}

// -------- tiled transpose + pack: in f32 [R,C] -> out bf16 [C,R] --------
__global__ __launch_bounds__(256) void transpose_pack(const float* __restrict__ in, u16* __restrict__ out,
                                                      int R, int C) {
  __shared__ u16 T[64][68];
  const int r0 = blockIdx.x * 64, c0 = blockIdx.y * 64;
  const int t = threadIdx.x;
  const int col = t & 63, rq = t >> 6;
#pragma unroll
  for (int s = 0; s < 16; ++s) {
    int row = s * 4 + rq;
    T[col][row] = f2bf(in[(size_t)(r0 + row) * C + c0 + col]);
  }
  __syncthreads();
#pragma unroll
  for (int s = 0; s < 16; ++s) {
    int crow = s * 4 + rq;
    out[(size_t)(c0 + crow) * R + r0 + col] = T[crow][col];
  }
}

// -------- bf16 GEMM: C[M,N] = A[M,K]*BT[N,K]^T + bias; 128x128, BK=64 --------
template <int OUTF32>
__global__ __launch_bounds__(256) void gemm_bt(const u16* __restrict__ A, const u16* __restrict__ BT,
                                               const float* __restrict__ bias, void* __restrict__ outp,
                                               int K, int N) {
  __shared__ u16 As[2][128 * 64];
  __shared__ u16 Bs[2][128 * 64];
  const int m0 = blockIdx.x * 128, n0 = blockIdx.y * 128;
  const int t = threadIdx.x, lane = t & 63, w = t >> 6;
  const int wr = w >> 1, wc = w & 1;
  const int l15 = lane & 15, l4 = lane >> 4;
  const int srow = lane >> 3, schunk = lane & 7;

  f32x4 acc[4][4] = {};

#define STAGE_G(buf, k0)                                                        \
  do {                                                                          \
    _Pragma("unroll") for (int i = 0; i < 4; ++i) {                             \
      int r0 = (i * 4 + w) * 8;                                                 \
      int r = r0 + srow;                                                        \
      int sc = (schunk ^ (r & 7)) * 8;                                          \
      gload16(&A[(size_t)(m0 + r) * K + (k0) + sc], &As[buf][r0 * 64]);         \
      gload16(&BT[(size_t)(n0 + r) * K + (k0) + sc], &Bs[buf][r0 * 64]);        \
    }                                                                           \
  } while (0)

  STAGE_G(0, 0);
  __syncthreads();
  const int nk = K / 64;
  int cur = 0;
  for (int t0 = 0; t0 < nk; ++t0) {
    if (t0 + 1 < nk) STAGE_G(cur ^ 1, (t0 + 1) * 64);
#pragma unroll
    for (int ks = 0; ks < 2; ++ks) {
      bf16x8 af[4], bfr[4];
#pragma unroll
      for (int g = 0; g < 4; ++g) {
        int ra = wr * 64 + g * 16 + l15;
        int rb = wc * 64 + g * 16 + l15;
        af[g]  = *(const bf16x8*)&As[cur][ra * 64 + ((ks * 4 + l4) ^ (ra & 7)) * 8];
        bfr[g] = *(const bf16x8*)&Bs[cur][rb * 64 + ((ks * 4 + l4) ^ (rb & 7)) * 8];
      }
#pragma unroll
      for (int mg = 0; mg < 4; ++mg)
#pragma unroll
        for (int ng = 0; ng < 4; ++ng)
          acc[mg][ng] = __builtin_amdgcn_mfma_f32_16x16x32_bf16(af[mg], bfr[ng], acc[mg][ng], 0, 0, 0);
    }
    __syncthreads();
    cur ^= 1;
  }
#undef STAGE_G
  const int rowb = m0 + wr * 64, colb = n0 + wc * 64;
#pragma unroll
  for (int mg = 0; mg < 4; ++mg)
#pragma unroll
    for (int ng = 0; ng < 4; ++ng) {
      int col = colb + ng * 16 + l15;
      float bv = bias[col];
#pragma unroll
      for (int j = 0; j < 4; ++j) {
        int row = rowb + mg * 16 + l4 * 4 + j;
        float val = acc[mg][ng][j] + bv;
        if (OUTF32) ((float*)outp)[(size_t)row * N + col] = val;
        else        ((u16*)outp)[(size_t)row * N + col] = f2bf(val);
      }
    }
}

// -------- fused attention --------
// grid = B*NH*16 blocks (128 q-rows each), 8 waves (512 thr), wave = 16 q-rows.
// All 512 blocks co-resident (2/CU, 60KB LDS).
// Pass 1: row sums of exp.  Pass 2: recompute logits bitwise-identically,
// direct f32 scores stores (issued early, drain under compute), PV from LDS.
__global__ __launch_bounds__(512, 4) void attn_fused(const u16* __restrict__ qkv, const float* __restrict__ mask,
                                                     float* __restrict__ scores, u16* __restrict__ attnout) {
  __shared__ u16 Ks[2][64 * 64];
  __shared__ u16 Vt[2][64 * 68];   // V^T, pad 68 (keeps write scatter off single-bank groups)
  __shared__ u16 Ps[8][16][72];    // per-wave bf16 P tile
  __shared__ float MB[S_LEN];      // mask bias
  const int bid = blockIdx.x;
  const int qt = bid & 15, h = (bid >> 4) & 15, b = bid >> 8;
  const int t = threadIdx.x, lane = t & 63, w = t >> 6;
  const int l15 = lane & 15, l4 = lane >> 4;
  const u16* kbase = qkv + (size_t)b * S_LEN * NQKV + D_MODEL + h * DK;
  const u16* vbase = kbase + D_MODEL;

  {  // mask bias -> LDS (read once, reused 64x per thread)
    float4 m4 = *(const float4*)&mask[b * S_LEN + t * 4];
    MB[t * 4 + 0] = -10000.0f * (1.0f - m4.x);
    MB[t * 4 + 1] = -10000.0f * (1.0f - m4.y);
    MB[t * 4 + 2] = -10000.0f * (1.0f - m4.z);
    MB[t * 4 + 3] = -10000.0f * (1.0f - m4.w);
  }

  // Q fragments, pre-scaled by 1/8 (exact in bf16)
  bf16x8 qf[2];
  {
    const int qrow = qt * 128 + w * 16 + l15;
    const u16* qp = qkv + (size_t)(b * S_LEN + qrow) * NQKV + h * DK;
#pragma unroll
    for (int ks = 0; ks < 2; ++ks) {
      union { bf16x8 v; u16 s[8]; } qa;
      qa.v = *(const bf16x8*)&qp[ks * 32 + l4 * 8];
#pragma unroll
      for (int e = 0; e < 8; ++e) qa.s[e] = f2bf(bf2f(qa.s[e]) * 0.125f);
      qf[ks] = qa.v;
    }
  }

  const int krow = w * 8 + (lane >> 3);
  const int kchunk = ((lane & 7) ^ (krow & 7)) * 8;
#define STAGE_K(buf, kt) \
  gload16(&kbase[(size_t)((kt) * 64 + krow) * NQKV + kchunk], &Ks[buf][w * 512])

  float ps4[4] = {0.f, 0.f, 0.f, 0.f};
  int cur = 0;
  // ---- pass 1: row sums ----
  STAGE_K(0, 0);
  __syncthreads();
  for (int kt = 0; kt < 32; ++kt) {
    if (kt + 1 < 32) STAGE_K(cur ^ 1, kt + 1);
    f32x4 sacc[4] = {};
#pragma unroll
    for (int ks = 0; ks < 2; ++ks) {
      bf16x8 kf[4];
#pragma unroll
      for (int n = 0; n < 4; ++n) {
        int kr = n * 16 + l15;
        kf[n] = *(const bf16x8*)&Ks[cur][kr * 64 + ((ks * 4 + l4) ^ (kr & 7)) * 8];
      }
#pragma unroll
      for (int n = 0; n < 4; ++n)
        sacc[n] = __builtin_amdgcn_mfma_f32_16x16x32_bf16(qf[ks], kf[n], sacc[n], 0, 0, 0);
    }
#pragma unroll
    for (int n = 0; n < 4; ++n) {
      float mb = MB[kt * 64 + n * 16 + l15];
#pragma unroll
      for (int j = 0; j < 4; ++j) ps4[j] += __expf(sacc[n][j] + mb);
    }
    __syncthreads();
    cur ^= 1;
  }
#pragma unroll
  for (int off = 1; off < 16; off <<= 1)
#pragma unroll
    for (int j = 0; j < 4; ++j) ps4[j] += __shfl_xor(ps4[j], off, 64);
  float inv4[4];
#pragma unroll
  for (int j = 0; j < 4; ++j) inv4[j] = 1.0f / ps4[j];

  // ---- pass 2 ----
  f32x4 oacc[4] = {};
  const int vr = t >> 3, vc = (t & 7) * 8;
  const size_t sbase = ((size_t)((b * NH + h) * S_LEN + qt * 128 + w * 16 + l4 * 4)) * S_LEN + l15;

  STAGE_K(0, 0);  // cur == 0 here
  {
    const u16* vp = &vbase[(size_t)vr * NQKV + vc];
    int4 va0 = *(const int4*)vp;
    const u16* s0 = (const u16*)&va0;
#pragma unroll
    for (int i = 0; i < 8; ++i) Vt[0][(vc + i) * 68 + vr] = s0[i];
  }
  __syncthreads();
  cur = 0;
  for (int kt = 0; kt < 32; ++kt) {
    const bool hn = (kt + 1 < 32);
    int4 va;
    if (hn) {
      STAGE_K(cur ^ 1, kt + 1);
      va = *(const int4*)&vbase[(size_t)((kt + 1) * 64 + vr) * NQKV + vc];
    }
    f32x4 sacc[4] = {};
#pragma unroll
    for (int ks = 0; ks < 2; ++ks) {
      bf16x8 kf[4];
#pragma unroll
      for (int n = 0; n < 4; ++n) {
        int kr = n * 16 + l15;
        kf[n] = *(const bf16x8*)&Ks[cur][kr * 64 + ((ks * 4 + l4) ^ (kr & 7)) * 8];
      }
#pragma unroll
      for (int n = 0; n < 4; ++n)
        sacc[n] = __builtin_amdgcn_mfma_f32_16x16x32_bf16(qf[ks], kf[n], sacc[n], 0, 0, 0);
    }
    // exp -> direct f32 scores stores (early issue) + bf16 P into LDS
#pragma unroll
    for (int n = 0; n < 4; ++n) {
      float mb = MB[kt * 64 + n * 16 + l15];
#pragma unroll
      for (int j = 0; j < 4; ++j) {
        float p = __expf(sacc[n][j] + mb) * inv4[j];
        scores[sbase + (size_t)j * S_LEN + kt * 64 + n * 16] = p;
        Ps[w][l4 * 4 + j][n * 16 + l15] = f2bf(p);
      }
    }
    // PV (Ps wave-private; Vt[cur] staged last iteration)
#pragma unroll
    for (int ks = 0; ks < 2; ++ks) {
      bf16x8 pa = *(const bf16x8*)&Ps[w][l15][ks * 32 + l4 * 8];
      bf16x8 vf[4];
#pragma unroll
      for (int dn = 0; dn < 4; ++dn)
        vf[dn] = *(const bf16x8*)&Vt[cur][(dn * 16 + l15) * 68 + ks * 32 + l4 * 8];
#pragma unroll
      for (int dn = 0; dn < 4; ++dn)
        oacc[dn] = __builtin_amdgcn_mfma_f32_16x16x32_bf16(pa, vf[dn], oacc[dn], 0, 0, 0);
    }
    if (hn) {  // write next V tile (buffer read last iter; all waves past that barrier)
      const u16* s0 = (const u16*)&va;
#pragma unroll
      for (int i = 0; i < 8; ++i) Vt[cur ^ 1][(vc + i) * 68 + vr] = s0[i];
    }
    __syncthreads();
    cur ^= 1;
  }
#undef STAGE_K
  // O write (bf16) for proj GEMM
#pragma unroll
  for (int dn = 0; dn < 4; ++dn) {
    int row = b * S_LEN + qt * 128 + w * 16 + l4 * 4;
    int col = h * DK + dn * 16 + l15;
#pragma unroll
    for (int j = 0; j < 4; ++j)
      attnout[(size_t)(row + j) * D_MODEL + col] = f2bf(oacc[dn][j]);
  }
}

extern "C" void kernel_launch(void* const* d_in, const int* in_sizes, int n_in,
                              void* d_out, int out_size, void* d_ws, size_t ws_size,
                              hipStream_t stream) {
  const float* x      = (const float*)d_in[0];
  const float* mask   = (const float*)d_in[1];
  const float* W_attn = (const float*)d_in[2];
  const float* b_attn = (const float*)d_in[3];
  const float* W_proj = (const float*)d_in[4];
  const float* b_proj = (const float*)d_in[5];
  float* out    = (float*)d_out;
  float* scores = out + (size_t)M_ROWS * D_MODEL;

  char* ws = (char*)d_ws;
  u16* xb     = (u16*)ws;                          // 8 MB  : x bf16 [4096,1024]
  u16* wqkvT  = (u16*)(ws + (size_t)(8  << 20));   // 6 MB  : W_attn^T bf16 [3072,1024]
  u16* wprojT = (u16*)(ws + (size_t)(14 << 20));   // 2 MB  : W_proj^T bf16 [1024,1024]
  u16* qkv    = (u16*)(ws + (size_t)(16 << 20));   // 24 MB : qkv bf16 [4096,3072]
  u16* attnb  = (u16*)(ws + (size_t)(40 << 20));   // 8 MB  : attn out bf16 [4096,1024]

  pack_bf16<<<(M_ROWS * D_MODEL) / (256 * 8), 256, 0, stream>>>(x, xb);
  transpose_pack<<<dim3(D_MODEL / 64, NQKV / 64), 256, 0, stream>>>(W_attn, wqkvT, D_MODEL, NQKV);
  transpose_pack<<<dim3(D_MODEL / 64, D_MODEL / 64), 256, 0, stream>>>(W_proj, wprojT, D_MODEL, D_MODEL);
  gemm_bt<0><<<dim3(M_ROWS / 128, NQKV / 128), 256, 0, stream>>>(xb, wqkvT, b_attn, (void*)qkv, D_MODEL, NQKV);
  attn_fused<<<BATCH * NH * (S_LEN / 128), 512, 0, stream>>>(qkv, mask, scores, attnb);
  gemm_bt<1><<<dim3(M_ROWS / 128, D_MODEL / 128), 256, 0, stream>>>(attnb, wprojT, b_proj, (void*)out, D_MODEL, D_MODEL);
}